// Round 1
// baseline (307.411 us; speedup 1.0000x reference)
//
#include <hip/hip_runtime.h>
#include <hip/hip_bf16.h>

// Problem constants (from reference setup_inputs)
constexpr int B  = 4096;   // batch rows
constexpr int D  = 784;    // feature dim (784 = 196 * 4, float4-clean)
constexpr int O1 = 8192;   // 2-term products
constexpr int O2 = 8192;   // 3-term products
constexpr int OT = O1 + O2; // 16384 output cols per row

constexpr int TPB  = 256;  // threads per block (4 waves)
constexpr int ROWS = 4;    // rows of x per block (LDS = 4*784*4 = 12544 B)
constexpr int VEC  = 4;    // output cols per thread (float4 store)
constexpr int COLS = TPB * VEC; // 1024 cols per block; 8192 % 1024 == 0 so
                                // a block never straddles the out1/out2 boundary

__global__ __launch_bounds__(TPB) void randomde_kernel(
    const float* __restrict__ x,
    const int*   __restrict__ idx1,
    const int*   __restrict__ idx2,
    float*       __restrict__ out)
{
    __shared__ float xs[ROWS][D];

    const int colChunk = blockIdx.x;           // 0..OT/COLS-1 (16)
    const int rowChunk = blockIdx.y;           // 0..B/ROWS-1 (1024)
    const int row0     = rowChunk * ROWS;
    const int tid      = threadIdx.x;

    // Stage ROWS contiguous rows of x into LDS with float4 loads.
    // row0*D floats is 16B-aligned (D*4 = 3136 = 196*16).
    {
        const float4* __restrict__ x4 = (const float4*)(x + (size_t)row0 * D);
        float4* xs4 = (float4*)&xs[0][0];
        constexpr int N4 = ROWS * (D / 4);     // 784 float4s
        #pragma unroll
        for (int i = tid; i < N4; i += TPB) {
            xs4[i] = x4[i];
        }
    }
    __syncthreads();

    const int colBase = colChunk * COLS + tid * VEC;  // global output col of elem 0

    float res[ROWS][VEC];

    if (colBase < O1) {
        // out1 region: 2-term products
        #pragma unroll
        for (int v = 0; v < VEC; ++v) {
            const int c  = colBase + v;
            const int a  = idx1[c * 2 + 0];
            const int b_ = idx1[c * 2 + 1];
            #pragma unroll
            for (int r = 0; r < ROWS; ++r) {
                res[r][v] = xs[r][a] * xs[r][b_];
            }
        }
    } else {
        // out2 region: 3-term products
        #pragma unroll
        for (int v = 0; v < VEC; ++v) {
            const int c  = colBase - O1 + v;
            const int a  = idx2[c * 3 + 0];
            const int b_ = idx2[c * 3 + 1];
            const int e  = idx2[c * 3 + 2];
            #pragma unroll
            for (int r = 0; r < ROWS; ++r) {
                res[r][v] = xs[r][a] * xs[r][b_] * xs[r][e];
            }
        }
    }

    // Coalesced float4 stores: wave writes 64*16 = 1 KiB contiguous per row.
    #pragma unroll
    for (int r = 0; r < ROWS; ++r) {
        float4 val = make_float4(res[r][0], res[r][1], res[r][2], res[r][3]);
        *(float4*)(out + (size_t)(row0 + r) * OT + colBase) = val;
    }
}

extern "C" void kernel_launch(void* const* d_in, const int* in_sizes, int n_in,
                              void* d_out, int out_size, void* d_ws, size_t ws_size,
                              hipStream_t stream) {
    const float* x    = (const float*)d_in[0];
    const int*   idx1 = (const int*)d_in[1];
    const int*   idx2 = (const int*)d_in[2];
    float*       out  = (float*)d_out;

    dim3 grid(OT / COLS, B / ROWS);   // (16, 1024)
    dim3 block(TPB);
    randomde_kernel<<<grid, block, 0, stream>>>(x, idx1, idx2, out);
}